// Round 4
// baseline (463.921 us; speedup 1.0000x reference)
//
#include <hip/hip_runtime.h>
#include <math.h>

// Problem constants (B, L, D fixed by the reference)
#define B_DIM 32
#define L_DIM 2048
#define D_DIM 1024
#define NC    32              // chunks per batch row for k_scores
#define CHUNK (L_DIM / NC)    // 64 rows per block
#define ROWS_PER_WAVE (CHUNK / 4)  // 16 rows per wave

__device__ __forceinline__ float wave_reduce_sum(float v) {
    #pragma unroll
    for (int off = 32; off > 0; off >>= 1)
        v += __shfl_xor(v, off, 64);
    return v;
}

// ---------------------------------------------------------------------------
// q[b,e] = sum_d query[b,d] * W_in[e,d]
// wave-per-e: stage W_in row in 4 float4/lane, loop b.
__global__ __launch_bounds__(256) void k_linear_in(
        const float* __restrict__ query, const float* __restrict__ W_in,
        float* __restrict__ q_out) {
    const int wave = threadIdx.x >> 6;
    const int lane = threadIdx.x & 63;
    const int e = blockIdx.x * 4 + wave;          // 0..1023
    const float4* W4 = (const float4*)(W_in + (size_t)e * D_DIM);
    float4 wrow[4];
    #pragma unroll
    for (int j = 0; j < 4; ++j) wrow[j] = W4[j * 64 + lane];
    for (int b = 0; b < B_DIM; ++b) {
        const float4* q4 = (const float4*)(query + (size_t)b * D_DIM);
        float local = 0.f;
        #pragma unroll
        for (int j = 0; j < 4; ++j) {
            float4 v = q4[j * 64 + lane];
            local += v.x * wrow[j].x + v.y * wrow[j].y
                   + v.z * wrow[j].z + v.w * wrow[j].w;
        }
        float s = wave_reduce_sum(local);
        if (lane == 0) q_out[(size_t)b * D_DIM + e] = s;
    }
}

// ---------------------------------------------------------------------------
// spart[b] = q[b,:] . w_att[0:D] + b_att
__global__ __launch_bounds__(64) void k_spart(
        const float* __restrict__ q, const float* __restrict__ w_att,
        const float* __restrict__ b_att, float* __restrict__ spart) {
    const int b = blockIdx.x;
    const int lane = threadIdx.x;
    const float4* q4 = (const float4*)(q + (size_t)b * D_DIM);
    const float4* w4 = (const float4*)(w_att);
    float local = 0.f;
    #pragma unroll
    for (int j = 0; j < 4; ++j) {
        float4 a = q4[j * 64 + lane];
        float4 w = w4[j * 64 + lane];
        local += a.x * w.x + a.y * w.y + a.z * w.z + a.w * w.w;
    }
    float s = wave_reduce_sum(local);
    if (lane == 0) spart[b] = s + b_att[0];
}

// ---------------------------------------------------------------------------
// The 256MB pass, 2-row software-pipelined: next row's loads are issued
// before the current row's reduce chain so HBM latency hides under the
// shuffle/transcendental work. Partials per block: pacc[b,c,:], pZ[b,c].
__global__ __launch_bounds__(256) void k_scores(
        const float* __restrict__ context, const float* __restrict__ w_att,
        const int* __restrict__ mask, const float* __restrict__ spart,
        float* __restrict__ out_weights,  // raw w written here (d_out section)
        float* __restrict__ pZ, float* __restrict__ pacc) {
    const int c = blockIdx.x;   // chunk
    const int b = blockIdx.y;   // batch
    const int wave = threadIdx.x >> 6;
    const int lane = threadIdx.x & 63;

    float4 wc[4];
    const float4* w4 = (const float4*)(w_att + D_DIM);
    #pragma unroll
    for (int j = 0; j < 4; ++j) wc[j] = w4[j * 64 + lane];

    const float sp = spart[b];
    float4 acc[4];
    #pragma unroll
    for (int j = 0; j < 4; ++j) acc[j] = make_float4(0.f, 0.f, 0.f, 0.f);
    float z = 0.f;

    const int l0 = c * CHUNK;
    const float* ctx_b = context + (size_t)b * L_DIM * D_DIM;
    const int* mask_b = mask + (size_t)b * L_DIM;

    // prologue: row 0 loads
    float4 v[4];
    {
        const float4* row4 = (const float4*)(ctx_b + (size_t)(l0 + wave) * D_DIM);
        #pragma unroll
        for (int j = 0; j < 4; ++j) v[j] = row4[j * 64 + lane];
    }

    for (int r = 0; r < ROWS_PER_WAVE; ++r) {
        const int l = l0 + r * 4 + wave;
        // issue next row's loads before consuming this row
        float4 vn[4] = {};
        if (r + 1 < ROWS_PER_WAVE) {
            const float4* rn = (const float4*)(ctx_b + (size_t)(l + 4) * D_DIM);
            #pragma unroll
            for (int j = 0; j < 4; ++j) vn[j] = rn[j * 64 + lane];
        }
        float local = 0.f;
        #pragma unroll
        for (int j = 0; j < 4; ++j)
            local += v[j].x * wc[j].x + v[j].y * wc[j].y
                   + v[j].z * wc[j].z + v[j].w * wc[j].w;
        float s = wave_reduce_sum(local);
        float w = (mask_b[l] == 0) ? 0.f : expf(tanhf(sp + s));
        if (lane == 0) out_weights[(size_t)b * L_DIM + l] = w;
        z += w;
        #pragma unroll
        for (int j = 0; j < 4; ++j) {
            acc[j].x += w * v[j].x;
            acc[j].y += w * v[j].y;
            acc[j].z += w * v[j].z;
            acc[j].w += w * v[j].w;
        }
        #pragma unroll
        for (int j = 0; j < 4; ++j) v[j] = vn[j];
    }

    // combine the 4 waves' partials via LDS
    __shared__ float sacc[4][D_DIM];   // 16 KB
    __shared__ float sz[4];
    #pragma unroll
    for (int j = 0; j < 4; ++j)
        ((float4*)sacc[wave])[j * 64 + lane] = acc[j];
    if (lane == 0) sz[wave] = z;
    __syncthreads();

    const int t = threadIdx.x;  // 0..255, each owns d = 4t..4t+3
    float4 s0 = ((const float4*)sacc[0])[t];
    float4 s1 = ((const float4*)sacc[1])[t];
    float4 s2 = ((const float4*)sacc[2])[t];
    float4 s3 = ((const float4*)sacc[3])[t];
    float4 tot;
    tot.x = s0.x + s1.x + s2.x + s3.x;
    tot.y = s0.y + s1.y + s2.y + s3.y;
    tot.z = s0.z + s1.z + s2.z + s3.z;
    tot.w = s0.w + s1.w + s2.w + s3.w;
    ((float4*)(pacc + ((size_t)(b * NC + c)) * D_DIM))[t] = tot;
    if (t == 0) pZ[b * NC + c] = sz[0] + sz[1] + sz[2] + sz[3];
}

// ---------------------------------------------------------------------------
// invZ[b] = 1/sum_c pZ (wave-parallel); mix_raw[b,:] = sum_c pacc (UNNORMALIZED
// — k_out folds invZ in by linearity); weights normalized in place.
__global__ __launch_bounds__(256) void k_reduce(
        const float* __restrict__ pacc, const float* __restrict__ pZ,
        float* __restrict__ mix_raw, float* __restrict__ invZ_out,
        float* __restrict__ out_weights) {
    const int b = blockIdx.x;
    const int t = threadIdx.x;
    __shared__ float sInvZ;
    if (t < 64) {
        float zv = (t < NC) ? pZ[b * NC + t] : 0.f;
        zv = wave_reduce_sum(zv);
        if (t == 0) {
            float inv = (zv > 0.f) ? 1.f / zv : 0.f;
            sInvZ = inv;
            invZ_out[b] = inv;
        }
    }
    __syncthreads();
    const float invZ = sInvZ;

    float4 tot = make_float4(0.f, 0.f, 0.f, 0.f);
    #pragma unroll 8
    for (int c = 0; c < NC; ++c) {
        float4 v = ((const float4*)(pacc + ((size_t)(b * NC + c)) * D_DIM))[t];
        tot.x += v.x; tot.y += v.y; tot.z += v.z; tot.w += v.w;
    }
    ((float4*)(mix_raw + (size_t)b * D_DIM))[t] = tot;

    float4* w4 = (float4*)(out_weights + (size_t)b * L_DIM);
    #pragma unroll
    for (int i = 0; i < L_DIM / (256 * 4); ++i) {   // 2 iterations
        float4 v = w4[i * 256 + t];
        v.x *= invZ; v.y *= invZ; v.z *= invZ; v.w *= invZ;
        w4[i * 256 + t] = v;
    }
}

// ---------------------------------------------------------------------------
// out[b,e] = tanh( invZ[b] * (mix_raw[b,:] . W_out[e,0:D]) + q[b,:] . W_out[e,D:2D] )
__global__ __launch_bounds__(256) void k_out(
        const float* __restrict__ mix_raw, const float* __restrict__ q,
        const float* __restrict__ invZ, const float* __restrict__ W_out,
        float* __restrict__ out) {
    const int wave = threadIdx.x >> 6;
    const int lane = threadIdx.x & 63;
    const int e = blockIdx.x * 4 + wave;
    const float4* W4 = (const float4*)(W_out + (size_t)e * (2 * D_DIM));
    float4 wrow[8];
    #pragma unroll
    for (int j = 0; j < 8; ++j) wrow[j] = W4[j * 64 + lane];
    for (int b = 0; b < B_DIM; ++b) {
        const float4* m4 = (const float4*)(mix_raw + (size_t)b * D_DIM);
        const float4* q4 = (const float4*)(q + (size_t)b * D_DIM);
        const float iz = invZ[b];
        float lmix = 0.f, lq = 0.f;
        #pragma unroll
        for (int j = 0; j < 4; ++j) {
            float4 v = m4[j * 64 + lane];
            lmix += v.x * wrow[j].x + v.y * wrow[j].y
                  + v.z * wrow[j].z + v.w * wrow[j].w;
        }
        #pragma unroll
        for (int j = 0; j < 4; ++j) {
            float4 v = q4[j * 64 + lane];
            lq += v.x * wrow[j + 4].x + v.y * wrow[j + 4].y
                + v.z * wrow[j + 4].z + v.w * wrow[j + 4].w;
        }
        float s = wave_reduce_sum(lmix * iz + lq);
        if (lane == 0) out[(size_t)b * D_DIM + e] = tanhf(s);
    }
}

// ---------------------------------------------------------------------------
extern "C" void kernel_launch(void* const* d_in, const int* in_sizes, int n_in,
                              void* d_out, int out_size, void* d_ws, size_t ws_size,
                              hipStream_t stream) {
    const float* query   = (const float*)d_in[0];  // [B,1,D]
    const float* context = (const float*)d_in[1];  // [B,L,D]
    const float* W_in    = (const float*)d_in[2];  // [D,D]
    const float* w_att   = (const float*)d_in[3];  // [2D]
    const float* b_att   = (const float*)d_in[4];  // [1]
    const float* W_out   = (const float*)d_in[5];  // [D,2D]
    const int*   mask    = (const int*)d_in[6];    // [B,L]

    float* out   = (float*)d_out;                  // [B,1,D] flat
    float* out_w = out + (size_t)B_DIM * D_DIM;    // [B,1,L] flat

    // workspace layout (floats), all float4-aligned
    float* ws    = (float*)d_ws;
    float* q     = ws;                               // B*D     = 32768
    float* spart = q + (size_t)B_DIM * D_DIM;        // B       = 32
    float* pZ    = spart + B_DIM;                    // B*NC    = 1024
    float* pacc  = pZ + B_DIM * NC;                  // B*NC*D  = 1048576
    float* mix   = pacc + (size_t)B_DIM * NC * D_DIM;// B*D     = 32768
    float* invZ  = mix + (size_t)B_DIM * D_DIM;      // B       = 32

    k_linear_in<<<D_DIM / 4, 256, 0, stream>>>(query, W_in, q);
    k_spart<<<B_DIM, 64, 0, stream>>>(q, w_att, b_att, spart);
    k_scores<<<dim3(NC, B_DIM), 256, 0, stream>>>(context, w_att, mask, spart,
                                                  out_w, pZ, pacc);
    k_reduce<<<B_DIM, 256, 0, stream>>>(pacc, pZ, mix, invZ, out_w);
    k_out<<<D_DIM / 4, 256, 0, stream>>>(mix, q, invZ, W_out, out);
}

// Round 7
// 433.468 us; speedup vs baseline: 1.0703x; 1.0703x over previous
//
#include <hip/hip_runtime.h>
#include <math.h>

// Problem constants (B, L, D fixed by the reference)
#define B_DIM 32
#define L_DIM 2048
#define D_DIM 1024
#define NC    64              // chunks per batch row for k_scores (8 blocks/CU)
#define CHUNK (L_DIM / NC)    // 32 rows per block
#define ROWS_PER_WAVE (CHUNK / 4)  // 8 rows per wave

__device__ __forceinline__ float wave_reduce_sum(float v) {
    #pragma unroll
    for (int off = 32; off > 0; off >>= 1)
        v += __shfl_xor(v, off, 64);
    return v;
}

// ---------------------------------------------------------------------------
// q[b,e] = sum_d query[b,d] * W_in[e,d]
// wave-per-e: stage W_in row in 4 float4/lane, loop b (unrolled for ILP
// across the independent shuffle-reduce chains).
__global__ __launch_bounds__(256) void k_linear_in(
        const float* __restrict__ query, const float* __restrict__ W_in,
        float* __restrict__ q_out) {
    const int wave = threadIdx.x >> 6;
    const int lane = threadIdx.x & 63;
    const int e = blockIdx.x * 4 + wave;          // 0..1023
    const float4* W4 = (const float4*)(W_in + (size_t)e * D_DIM);
    float4 wrow[4];
    #pragma unroll
    for (int j = 0; j < 4; ++j) wrow[j] = W4[j * 64 + lane];
    #pragma unroll 4
    for (int b = 0; b < B_DIM; ++b) {
        const float4* q4 = (const float4*)(query + (size_t)b * D_DIM);
        float local = 0.f;
        #pragma unroll
        for (int j = 0; j < 4; ++j) {
            float4 v = q4[j * 64 + lane];
            local += v.x * wrow[j].x + v.y * wrow[j].y
                   + v.z * wrow[j].z + v.w * wrow[j].w;
        }
        float s = wave_reduce_sum(local);
        if (lane == 0) q_out[(size_t)b * D_DIM + e] = s;
    }
}

// ---------------------------------------------------------------------------
// The 256MB pass. Per block (chunk c, batch b):
//   wave 0 recomputes spart[b] = q[b,:].w_att[:D] + b_att (4KB, L2-resident)
//   all waves: per row, score=tanh(spart + ctx_row.w_att[D:]), w=mask?exp:0
//   raw w -> out_weights; acc += w*ctx_row; partials pacc[b,c,:], pZ[b,c].
__global__ __launch_bounds__(256) void k_scores(
        const float* __restrict__ context, const float* __restrict__ w_att,
        const int* __restrict__ mask, const float* __restrict__ q,
        const float* __restrict__ b_att,
        float* __restrict__ out_weights,  // raw w written here (d_out section)
        float* __restrict__ pZ, float* __restrict__ pacc) {
    const int c = blockIdx.x;   // chunk
    const int b = blockIdx.y;   // batch
    const int wave = threadIdx.x >> 6;
    const int lane = threadIdx.x & 63;

    __shared__ float ssp;
    __shared__ float sacc[4][D_DIM];   // 16 KB
    __shared__ float sz[4];

    float4 wc[4];
    const float4* w4 = (const float4*)(w_att + D_DIM);
    #pragma unroll
    for (int j = 0; j < 4; ++j) wc[j] = w4[j * 64 + lane];

    const int l0 = c * CHUNK;
    const float* ctx_b = context + (size_t)b * L_DIM * D_DIM;
    const int* mask_b = mask + (size_t)b * L_DIM;

    // prologue: row 0 loads (issued before the spart barrier so HBM latency
    // hides under wave 0's dot product)
    float4 v[4];
    {
        const float4* row4 = (const float4*)(ctx_b + (size_t)(l0 + wave) * D_DIM);
        #pragma unroll
        for (int j = 0; j < 4; ++j) v[j] = row4[j * 64 + lane];
    }

    if (wave == 0) {   // recompute spart[b] locally (q row is L2-hot)
        const float4* q4 = (const float4*)(q + (size_t)b * D_DIM);
        const float4* wq = (const float4*)(w_att);
        float local = 0.f;
        #pragma unroll
        for (int j = 0; j < 4; ++j) {
            float4 a = q4[j * 64 + lane];
            float4 w = wq[j * 64 + lane];
            local += a.x * w.x + a.y * w.y + a.z * w.z + a.w * w.w;
        }
        float s = wave_reduce_sum(local);
        if (lane == 0) ssp = s + b_att[0];
    }
    __syncthreads();
    const float sp = ssp;

    float4 acc[4];
    #pragma unroll
    for (int j = 0; j < 4; ++j) acc[j] = make_float4(0.f, 0.f, 0.f, 0.f);
    float z = 0.f;

    for (int r = 0; r < ROWS_PER_WAVE; ++r) {
        const int l = l0 + r * 4 + wave;
        // issue next row's loads before consuming this row
        float4 vn[4] = {};
        if (r + 1 < ROWS_PER_WAVE) {
            const float4* rn = (const float4*)(ctx_b + (size_t)(l + 4) * D_DIM);
            #pragma unroll
            for (int j = 0; j < 4; ++j) vn[j] = rn[j * 64 + lane];
        }
        float local = 0.f;
        #pragma unroll
        for (int j = 0; j < 4; ++j)
            local += v[j].x * wc[j].x + v[j].y * wc[j].y
                   + v[j].z * wc[j].z + v[j].w * wc[j].w;
        float s = wave_reduce_sum(local);
        float w = (mask_b[l] == 0) ? 0.f : expf(tanhf(sp + s));
        if (lane == 0) out_weights[(size_t)b * L_DIM + l] = w;
        z += w;
        #pragma unroll
        for (int j = 0; j < 4; ++j) {
            acc[j].x += w * v[j].x;
            acc[j].y += w * v[j].y;
            acc[j].z += w * v[j].z;
            acc[j].w += w * v[j].w;
        }
        #pragma unroll
        for (int j = 0; j < 4; ++j) v[j] = vn[j];
    }

    // combine the 4 waves' partials via LDS
    #pragma unroll
    for (int j = 0; j < 4; ++j)
        ((float4*)sacc[wave])[j * 64 + lane] = acc[j];
    if (lane == 0) sz[wave] = z;
    __syncthreads();

    const int t = threadIdx.x;  // 0..255, each owns d = 4t..4t+3
    float4 s0 = ((const float4*)sacc[0])[t];
    float4 s1 = ((const float4*)sacc[1])[t];
    float4 s2 = ((const float4*)sacc[2])[t];
    float4 s3 = ((const float4*)sacc[3])[t];
    float4 tot;
    tot.x = s0.x + s1.x + s2.x + s3.x;
    tot.y = s0.y + s1.y + s2.y + s3.y;
    tot.z = s0.z + s1.z + s2.z + s3.z;
    tot.w = s0.w + s1.w + s2.w + s3.w;
    ((float4*)(pacc + ((size_t)(b * NC + c)) * D_DIM))[t] = tot;
    if (t == 0) pZ[b * NC + c] = sz[0] + sz[1] + sz[2] + sz[3];
}

// ---------------------------------------------------------------------------
// invZ[b] = 1/sum_c pZ (wave-parallel, 64 lanes = 64 chunks);
// mix_raw[b,:] = sum_c pacc (UNNORMALIZED — k_out folds invZ by linearity);
// weights normalized in place.
__global__ __launch_bounds__(256) void k_reduce(
        const float* __restrict__ pacc, const float* __restrict__ pZ,
        float* __restrict__ mix_raw, float* __restrict__ invZ_out,
        float* __restrict__ out_weights) {
    const int b = blockIdx.x;
    const int t = threadIdx.x;
    __shared__ float sInvZ;
    if (t < 64) {
        float zv = pZ[b * NC + t];          // NC == 64 == wave width
        zv = wave_reduce_sum(zv);
        if (t == 0) {
            float inv = (zv > 0.f) ? 1.f / zv : 0.f;
            sInvZ = inv;
            invZ_out[b] = inv;
        }
    }
    __syncthreads();
    const float invZ = sInvZ;

    float4 tot = make_float4(0.f, 0.f, 0.f, 0.f);
    #pragma unroll 8
    for (int c = 0; c < NC; ++c) {
        float4 v = ((const float4*)(pacc + ((size_t)(b * NC + c)) * D_DIM))[t];
        tot.x += v.x; tot.y += v.y; tot.z += v.z; tot.w += v.w;
    }
    ((float4*)(mix_raw + (size_t)b * D_DIM))[t] = tot;

    float4* w4 = (float4*)(out_weights + (size_t)b * L_DIM);
    #pragma unroll
    for (int i = 0; i < L_DIM / (256 * 4); ++i) {   // 2 iterations
        float4 v = w4[i * 256 + t];
        v.x *= invZ; v.y *= invZ; v.z *= invZ; v.w *= invZ;
        w4[i * 256 + t] = v;
    }
}

// ---------------------------------------------------------------------------
// out[b,e] = tanh( invZ[b]*(mix_raw[b,:].W_out[e,0:D]) + q[b,:].W_out[e,D:2D] )
__global__ __launch_bounds__(256) void k_out(
        const float* __restrict__ mix_raw, const float* __restrict__ q,
        const float* __restrict__ invZ, const float* __restrict__ W_out,
        float* __restrict__ out) {
    const int wave = threadIdx.x >> 6;
    const int lane = threadIdx.x & 63;
    const int e = blockIdx.x * 4 + wave;
    const float4* W4 = (const float4*)(W_out + (size_t)e * (2 * D_DIM));
    float4 wrow[8];
    #pragma unroll
    for (int j = 0; j < 8; ++j) wrow[j] = W4[j * 64 + lane];
    #pragma unroll 2
    for (int b = 0; b < B_DIM; ++b) {
        const float4* m4 = (const float4*)(mix_raw + (size_t)b * D_DIM);
        const float4* q4 = (const float4*)(q + (size_t)b * D_DIM);
        const float iz = invZ[b];
        float lmix = 0.f, lq = 0.f;
        #pragma unroll
        for (int j = 0; j < 4; ++j) {
            float4 v = m4[j * 64 + lane];
            lmix += v.x * wrow[j].x + v.y * wrow[j].y
                  + v.z * wrow[j].z + v.w * wrow[j].w;
        }
        #pragma unroll
        for (int j = 0; j < 4; ++j) {
            float4 v = q4[j * 64 + lane];
            lq += v.x * wrow[j + 4].x + v.y * wrow[j + 4].y
                + v.z * wrow[j + 4].z + v.w * wrow[j + 4].w;
        }
        float s = wave_reduce_sum(lmix * iz + lq);
        if (lane == 0) out[(size_t)b * D_DIM + e] = tanhf(s);
    }
}

// ---------------------------------------------------------------------------
extern "C" void kernel_launch(void* const* d_in, const int* in_sizes, int n_in,
                              void* d_out, int out_size, void* d_ws, size_t ws_size,
                              hipStream_t stream) {
    const float* query   = (const float*)d_in[0];  // [B,1,D]
    const float* context = (const float*)d_in[1];  // [B,L,D]
    const float* W_in    = (const float*)d_in[2];  // [D,D]
    const float* w_att   = (const float*)d_in[3];  // [2D]
    const float* b_att   = (const float*)d_in[4];  // [1]
    const float* W_out   = (const float*)d_in[5];  // [D,2D]
    const int*   mask    = (const int*)d_in[6];    // [B,L]

    float* out   = (float*)d_out;                  // [B,1,D] flat
    float* out_w = out + (size_t)B_DIM * D_DIM;    // [B,1,L] flat

    // workspace layout (floats), all float4-aligned
    float* ws    = (float*)d_ws;
    float* q     = ws;                               // B*D      = 32768
    float* pZ    = q + (size_t)B_DIM * D_DIM;        // B*NC     = 2048
    float* pacc  = pZ + B_DIM * NC;                  // B*NC*D   = 2097152
    float* mix   = pacc + (size_t)B_DIM * NC * D_DIM;// B*D      = 32768
    float* invZ  = mix + (size_t)B_DIM * D_DIM;      // B        = 32

    k_linear_in<<<D_DIM / 4, 256, 0, stream>>>(query, W_in, q);
    k_scores<<<dim3(NC, B_DIM), 256, 0, stream>>>(context, w_att, mask, q,
                                                  b_att, out_w, pZ, pacc);
    k_reduce<<<B_DIM, 256, 0, stream>>>(pacc, pZ, mix, invZ, out_w);
    k_out<<<D_DIM / 4, 256, 0, stream>>>(mix, q, invZ, W_out, out);
}

// Round 8
// 433.213 us; speedup vs baseline: 1.0709x; 1.0006x over previous
//
#include <hip/hip_runtime.h>
#include <math.h>

// Problem constants (B, L, D fixed by the reference)
#define B_DIM 32
#define L_DIM 2048
#define D_DIM 1024
#define NC    64              // chunks per batch row for k_scores (8 blocks/CU)
#define CHUNK (L_DIM / NC)    // 32 rows per block
#define ROWS_PER_WAVE (CHUNK / 4)  // 8 rows per wave

__device__ __forceinline__ float wave_reduce_sum(float v) {
    #pragma unroll
    for (int off = 32; off > 0; off >>= 1)
        v += __shfl_xor(v, off, 64);
    return v;
}

// ---------------------------------------------------------------------------
// q[b,e] = sum_d query[b,d] * W_in[e,d]
// wave-per-e: stage W_in row in 4 float4/lane, loop b (unrolled for ILP
// across the independent shuffle-reduce chains).
__global__ __launch_bounds__(256) void k_linear_in(
        const float* __restrict__ query, const float* __restrict__ W_in,
        float* __restrict__ q_out) {
    const int wave = threadIdx.x >> 6;
    const int lane = threadIdx.x & 63;
    const int e = blockIdx.x * 4 + wave;          // 0..1023
    const float4* W4 = (const float4*)(W_in + (size_t)e * D_DIM);
    float4 wrow[4];
    #pragma unroll
    for (int j = 0; j < 4; ++j) wrow[j] = W4[j * 64 + lane];
    #pragma unroll 4
    for (int b = 0; b < B_DIM; ++b) {
        const float4* q4 = (const float4*)(query + (size_t)b * D_DIM);
        float local = 0.f;
        #pragma unroll
        for (int j = 0; j < 4; ++j) {
            float4 v = q4[j * 64 + lane];
            local += v.x * wrow[j].x + v.y * wrow[j].y
                   + v.z * wrow[j].z + v.w * wrow[j].w;
        }
        float s = wave_reduce_sum(local);
        if (lane == 0) q_out[(size_t)b * D_DIM + e] = s;
    }
}

// ---------------------------------------------------------------------------
// The 256MB pass. Per block (chunk c, batch b):
//   wave 0 recomputes spart[b] = q[b,:].w_att[:D] + b_att (4KB, L2-resident)
//   all waves: per row, score=tanh(spart + ctx_row.w_att[D:]), w=mask?exp:0
//   raw w -> out_weights; acc += w*ctx_row.
// Epilogue: block partial atomically accumulated into mix_raw (no pacc
// round-trip); pZ[b,c] written for the Z reduce.
__global__ __launch_bounds__(256) void k_scores(
        const float* __restrict__ context, const float* __restrict__ w_att,
        const int* __restrict__ mask, const float* __restrict__ q,
        const float* __restrict__ b_att,
        float* __restrict__ out_weights,  // raw w written here (d_out section)
        float* __restrict__ pZ, float* __restrict__ mix_raw) {
    const int c = blockIdx.x;   // chunk
    const int b = blockIdx.y;   // batch
    const int wave = threadIdx.x >> 6;
    const int lane = threadIdx.x & 63;

    __shared__ float ssp;
    __shared__ float sacc[4][D_DIM];   // 16 KB
    __shared__ float sz[4];

    float4 wc[4];
    const float4* w4 = (const float4*)(w_att + D_DIM);
    #pragma unroll
    for (int j = 0; j < 4; ++j) wc[j] = w4[j * 64 + lane];

    const int l0 = c * CHUNK;
    const float* ctx_b = context + (size_t)b * L_DIM * D_DIM;
    const int* mask_b = mask + (size_t)b * L_DIM;

    // prologue: row 0 loads (issued before the spart barrier so HBM latency
    // hides under wave 0's dot product)
    float4 v[4];
    {
        const float4* row4 = (const float4*)(ctx_b + (size_t)(l0 + wave) * D_DIM);
        #pragma unroll
        for (int j = 0; j < 4; ++j) v[j] = row4[j * 64 + lane];
    }

    if (wave == 0) {   // recompute spart[b] locally (q row is L2-hot)
        const float4* q4 = (const float4*)(q + (size_t)b * D_DIM);
        const float4* wq = (const float4*)(w_att);
        float local = 0.f;
        #pragma unroll
        for (int j = 0; j < 4; ++j) {
            float4 a = q4[j * 64 + lane];
            float4 w = wq[j * 64 + lane];
            local += a.x * w.x + a.y * w.y + a.z * w.z + a.w * w.w;
        }
        float s = wave_reduce_sum(local);
        if (lane == 0) ssp = s + b_att[0];
    }
    __syncthreads();
    const float sp = ssp;

    float4 acc[4];
    #pragma unroll
    for (int j = 0; j < 4; ++j) acc[j] = make_float4(0.f, 0.f, 0.f, 0.f);
    float z = 0.f;

    for (int r = 0; r < ROWS_PER_WAVE; ++r) {
        const int l = l0 + r * 4 + wave;
        // issue next row's loads before consuming this row
        float4 vn[4] = {};
        if (r + 1 < ROWS_PER_WAVE) {
            const float4* rn = (const float4*)(ctx_b + (size_t)(l + 4) * D_DIM);
            #pragma unroll
            for (int j = 0; j < 4; ++j) vn[j] = rn[j * 64 + lane];
        }
        float local = 0.f;
        #pragma unroll
        for (int j = 0; j < 4; ++j)
            local += v[j].x * wc[j].x + v[j].y * wc[j].y
                   + v[j].z * wc[j].z + v[j].w * wc[j].w;
        float s = wave_reduce_sum(local);
        float w = (mask_b[l] == 0) ? 0.f : expf(tanhf(sp + s));
        if (lane == 0) out_weights[(size_t)b * L_DIM + l] = w;
        z += w;
        #pragma unroll
        for (int j = 0; j < 4; ++j) {
            acc[j].x += w * v[j].x;
            acc[j].y += w * v[j].y;
            acc[j].z += w * v[j].z;
            acc[j].w += w * v[j].w;
        }
        #pragma unroll
        for (int j = 0; j < 4; ++j) v[j] = vn[j];
    }

    // combine the 4 waves' partials via LDS
    #pragma unroll
    for (int j = 0; j < 4; ++j)
        ((float4*)sacc[wave])[j * 64 + lane] = acc[j];
    if (lane == 0) sz[wave] = z;
    __syncthreads();

    const int t = threadIdx.x;  // 0..255, each owns d = 4t..4t+3
    float4 s0 = ((const float4*)sacc[0])[t];
    float4 s1 = ((const float4*)sacc[1])[t];
    float4 s2 = ((const float4*)sacc[2])[t];
    float4 s3 = ((const float4*)sacc[3])[t];
    float* dst = mix_raw + (size_t)b * D_DIM + 4 * t;
    atomicAdd(dst + 0, s0.x + s1.x + s2.x + s3.x);
    atomicAdd(dst + 1, s0.y + s1.y + s2.y + s3.y);
    atomicAdd(dst + 2, s0.z + s1.z + s2.z + s3.z);
    atomicAdd(dst + 3, s0.w + s1.w + s2.w + s3.w);
    if (t == 0) pZ[b * NC + c] = sz[0] + sz[1] + sz[2] + sz[3];
}

// ---------------------------------------------------------------------------
// invZ[b] = 1/sum_c pZ (wave-parallel, 64 lanes = 64 chunks);
// weights normalized in place. (mix normalization is folded into k_out.)
__global__ __launch_bounds__(256) void k_znorm(
        const float* __restrict__ pZ, float* __restrict__ invZ_out,
        float* __restrict__ out_weights) {
    const int b = blockIdx.x;
    const int t = threadIdx.x;
    __shared__ float sInvZ;
    if (t < 64) {
        float zv = pZ[b * NC + t];          // NC == 64 == wave width
        zv = wave_reduce_sum(zv);
        if (t == 0) {
            float inv = (zv > 0.f) ? 1.f / zv : 0.f;
            sInvZ = inv;
            invZ_out[b] = inv;
        }
    }
    __syncthreads();
    const float invZ = sInvZ;

    float4* w4 = (float4*)(out_weights + (size_t)b * L_DIM);
    #pragma unroll
    for (int i = 0; i < L_DIM / (256 * 4); ++i) {   // 2 iterations
        float4 v = w4[i * 256 + t];
        v.x *= invZ; v.y *= invZ; v.z *= invZ; v.w *= invZ;
        w4[i * 256 + t] = v;
    }
}

// ---------------------------------------------------------------------------
// out[b,e] = tanh( invZ[b]*(mix_raw[b,:].W_out[e,0:D]) + q[b,:].W_out[e,D:2D] )
__global__ __launch_bounds__(256) void k_out(
        const float* __restrict__ mix_raw, const float* __restrict__ q,
        const float* __restrict__ invZ, const float* __restrict__ W_out,
        float* __restrict__ out) {
    const int wave = threadIdx.x >> 6;
    const int lane = threadIdx.x & 63;
    const int e = blockIdx.x * 4 + wave;
    const float4* W4 = (const float4*)(W_out + (size_t)e * (2 * D_DIM));
    float4 wrow[8];
    #pragma unroll
    for (int j = 0; j < 8; ++j) wrow[j] = W4[j * 64 + lane];
    #pragma unroll 2
    for (int b = 0; b < B_DIM; ++b) {
        const float4* m4 = (const float4*)(mix_raw + (size_t)b * D_DIM);
        const float4* q4 = (const float4*)(q + (size_t)b * D_DIM);
        const float iz = invZ[b];
        float lmix = 0.f, lq = 0.f;
        #pragma unroll
        for (int j = 0; j < 4; ++j) {
            float4 v = m4[j * 64 + lane];
            lmix += v.x * wrow[j].x + v.y * wrow[j].y
                  + v.z * wrow[j].z + v.w * wrow[j].w;
        }
        #pragma unroll
        for (int j = 0; j < 4; ++j) {
            float4 v = q4[j * 64 + lane];
            lq += v.x * wrow[j + 4].x + v.y * wrow[j + 4].y
                + v.z * wrow[j + 4].z + v.w * wrow[j + 4].w;
        }
        float s = wave_reduce_sum(lmix * iz + lq);
        if (lane == 0) out[(size_t)b * D_DIM + e] = tanhf(s);
    }
}

// ---------------------------------------------------------------------------
extern "C" void kernel_launch(void* const* d_in, const int* in_sizes, int n_in,
                              void* d_out, int out_size, void* d_ws, size_t ws_size,
                              hipStream_t stream) {
    const float* query   = (const float*)d_in[0];  // [B,1,D]
    const float* context = (const float*)d_in[1];  // [B,L,D]
    const float* W_in    = (const float*)d_in[2];  // [D,D]
    const float* w_att   = (const float*)d_in[3];  // [2D]
    const float* b_att   = (const float*)d_in[4];  // [1]
    const float* W_out   = (const float*)d_in[5];  // [D,2D]
    const int*   mask    = (const int*)d_in[6];    // [B,L]

    float* out   = (float*)d_out;                  // [B,1,D] flat
    float* out_w = out + (size_t)B_DIM * D_DIM;    // [B,1,L] flat

    // workspace layout (floats), all float4-aligned
    float* ws    = (float*)d_ws;
    float* q     = ws;                               // B*D  = 32768
    float* pZ    = q + (size_t)B_DIM * D_DIM;        // B*NC = 2048
    float* mix   = pZ + B_DIM * NC;                  // B*D  = 32768 (atomic acc)
    float* invZ  = mix + (size_t)B_DIM * D_DIM;      // B    = 32

    // zero the atomic accumulator (ws is re-poisoned to 0xAA every iteration)
    hipMemsetAsync(mix, 0, (size_t)B_DIM * D_DIM * sizeof(float), stream);

    k_linear_in<<<D_DIM / 4, 256, 0, stream>>>(query, W_in, q);
    k_scores<<<dim3(NC, B_DIM), 256, 0, stream>>>(context, w_att, mask, q,
                                                  b_att, out_w, pZ, mix);
    k_znorm<<<B_DIM, 256, 0, stream>>>(pZ, invZ, out_w);
    k_out<<<D_DIM / 4, 256, 0, stream>>>(mix, q, invZ, W_out, out);
}

// Round 10
// 430.895 us; speedup vs baseline: 1.0766x; 1.0054x over previous
//
#include <hip/hip_runtime.h>
#include <math.h>

// Problem constants (B, L, D fixed by the reference)
#define B_DIM 32
#define L_DIM 2048
#define D_DIM 1024
#define NC    64              // chunks per batch row for k_scores (8 blocks/CU)
#define CHUNK (L_DIM / NC)    // 32 rows per block
#define ROWS_PER_WAVE (CHUNK / 4)  // 8 rows per wave

__device__ __forceinline__ float wave_reduce_sum(float v) {
    #pragma unroll
    for (int off = 32; off > 0; off >>= 1)
        v += __shfl_xor(v, off, 64);
    return v;
}

// ---------------------------------------------------------------------------
// q[b,e] = sum_d query[b,d] * W_in[e,d]
// wave-per-e: stage W_in row in 4 float4/lane, loop b (unrolled for ILP).
// Also zeroes the atomic mix accumulator (replaces a memset dispatch;
// kernel-boundary ordering makes it visible to k_scores).
__global__ __launch_bounds__(256) void k_linear_in(
        const float* __restrict__ query, const float* __restrict__ W_in,
        float* __restrict__ q_out, float* __restrict__ mix_zero) {
    const int t = threadIdx.x;
    if (t < 32)   // 256 blocks x 32 float4 = 8192 float4 = 32768 floats
        ((float4*)mix_zero)[blockIdx.x * 32 + t] = make_float4(0.f, 0.f, 0.f, 0.f);

    const int wave = threadIdx.x >> 6;
    const int lane = threadIdx.x & 63;
    const int e = blockIdx.x * 4 + wave;          // 0..1023
    const float4* W4 = (const float4*)(W_in + (size_t)e * D_DIM);
    float4 wrow[4];
    #pragma unroll
    for (int j = 0; j < 4; ++j) wrow[j] = W4[j * 64 + lane];
    #pragma unroll 4
    for (int b = 0; b < B_DIM; ++b) {
        const float4* q4 = (const float4*)(query + (size_t)b * D_DIM);
        float local = 0.f;
        #pragma unroll
        for (int j = 0; j < 4; ++j) {
            float4 v = q4[j * 64 + lane];
            local += v.x * wrow[j].x + v.y * wrow[j].y
                   + v.z * wrow[j].z + v.w * wrow[j].w;
        }
        float s = wave_reduce_sum(local);
        if (lane == 0) q_out[(size_t)b * D_DIM + e] = s;
    }
}

// ---------------------------------------------------------------------------
// The 256MB pass. Per block (chunk c, batch b):
//   wave 0 recomputes spart[b] = q[b,:].w_att[:D] + b_att (4KB, L2-resident)
//   all waves: per row, score=tanh(spart + ctx_row.w_att[D:]), w=mask?exp:0
//   raw w -> out_weights; acc += w*ctx_row.
// Epilogue: block partial atomically accumulated into mix_raw; pZ[b,c]
// written for the Z reduce.
__global__ __launch_bounds__(256) void k_scores(
        const float* __restrict__ context, const float* __restrict__ w_att,
        const int* __restrict__ mask, const float* __restrict__ q,
        const float* __restrict__ b_att,
        float* __restrict__ out_weights,  // raw w written here (d_out section)
        float* __restrict__ pZ, float* __restrict__ mix_raw) {
    const int c = blockIdx.x;   // chunk
    const int b = blockIdx.y;   // batch
    const int wave = threadIdx.x >> 6;
    const int lane = threadIdx.x & 63;

    __shared__ float ssp;
    __shared__ float sacc[4][D_DIM];   // 16 KB
    __shared__ float sz[4];

    float4 wc[4];
    const float4* w4 = (const float4*)(w_att + D_DIM);
    #pragma unroll
    for (int j = 0; j < 4; ++j) wc[j] = w4[j * 64 + lane];

    const int l0 = c * CHUNK;
    const float* ctx_b = context + (size_t)b * L_DIM * D_DIM;
    const int* mask_b = mask + (size_t)b * L_DIM;

    // prologue: row 0 loads (issued before the spart barrier so HBM latency
    // hides under wave 0's dot product)
    float4 v[4];
    {
        const float4* row4 = (const float4*)(ctx_b + (size_t)(l0 + wave) * D_DIM);
        #pragma unroll
        for (int j = 0; j < 4; ++j) v[j] = row4[j * 64 + lane];
    }

    if (wave == 0) {   // recompute spart[b] locally (q row is L2-hot)
        const float4* q4 = (const float4*)(q + (size_t)b * D_DIM);
        const float4* wq = (const float4*)(w_att);
        float local = 0.f;
        #pragma unroll
        for (int j = 0; j < 4; ++j) {
            float4 a = q4[j * 64 + lane];
            float4 w = wq[j * 64 + lane];
            local += a.x * w.x + a.y * w.y + a.z * w.z + a.w * w.w;
        }
        float s = wave_reduce_sum(local);
        if (lane == 0) ssp = s + b_att[0];
    }
    __syncthreads();
    const float sp = ssp;

    float4 acc[4];
    #pragma unroll
    for (int j = 0; j < 4; ++j) acc[j] = make_float4(0.f, 0.f, 0.f, 0.f);
    float z = 0.f;

    for (int r = 0; r < ROWS_PER_WAVE; ++r) {
        const int l = l0 + r * 4 + wave;
        // issue next row's loads before consuming this row
        float4 vn[4] = {};
        if (r + 1 < ROWS_PER_WAVE) {
            const float4* rn = (const float4*)(ctx_b + (size_t)(l + 4) * D_DIM);
            #pragma unroll
            for (int j = 0; j < 4; ++j) vn[j] = rn[j * 64 + lane];
        }
        float local = 0.f;
        #pragma unroll
        for (int j = 0; j < 4; ++j)
            local += v[j].x * wc[j].x + v[j].y * wc[j].y
                   + v[j].z * wc[j].z + v[j].w * wc[j].w;
        float s = wave_reduce_sum(local);
        float w = (mask_b[l] == 0) ? 0.f : expf(tanhf(sp + s));
        if (lane == 0) out_weights[(size_t)b * L_DIM + l] = w;
        z += w;
        #pragma unroll
        for (int j = 0; j < 4; ++j) {
            acc[j].x += w * v[j].x;
            acc[j].y += w * v[j].y;
            acc[j].z += w * v[j].z;
            acc[j].w += w * v[j].w;
        }
        #pragma unroll
        for (int j = 0; j < 4; ++j) v[j] = vn[j];
    }

    // combine the 4 waves' partials via LDS
    #pragma unroll
    for (int j = 0; j < 4; ++j)
        ((float4*)sacc[wave])[j * 64 + lane] = acc[j];
    if (lane == 0) sz[wave] = z;
    __syncthreads();

    const int t = threadIdx.x;  // 0..255, each owns d = 4t..4t+3
    float4 s0 = ((const float4*)sacc[0])[t];
    float4 s1 = ((const float4*)sacc[1])[t];
    float4 s2 = ((const float4*)sacc[2])[t];
    float4 s3 = ((const float4*)sacc[3])[t];
    float* dst = mix_raw + (size_t)b * D_DIM + 4 * t;
    atomicAdd(dst + 0, s0.x + s1.x + s2.x + s3.x);
    atomicAdd(dst + 1, s0.y + s1.y + s2.y + s3.y);
    atomicAdd(dst + 2, s0.z + s1.z + s2.z + s3.z);
    atomicAdd(dst + 3, s0.w + s1.w + s2.w + s3.w);
    if (t == 0) pZ[b * NC + c] = sz[0] + sz[1] + sz[2] + sz[3];
}

// ---------------------------------------------------------------------------
// Fused epilogue (one dispatch):
//   Phase 1: every block recomputes invZ[b] for all 32 b from pZ (2KB, L2-hot;
//            wave w reduces b = 8w..8w+7, 64 lanes = 64 chunks each).
//   Phase 2: block normalizes its 256-float slice of out_weights.
//   Phase 3: out[b,e] = tanh(invZ[b]*(mix_raw.W_out[e,:D]) + q.W_out[e,D:]).
__global__ __launch_bounds__(256) void k_out(
        const float* __restrict__ mix_raw, const float* __restrict__ q,
        const float* __restrict__ pZ, const float* __restrict__ W_out,
        float* __restrict__ out, float* __restrict__ out_weights) {
    const int wave = threadIdx.x >> 6;
    const int lane = threadIdx.x & 63;
    const int t = threadIdx.x;

    __shared__ float sInvZ[B_DIM];
    #pragma unroll
    for (int i = 0; i < 8; ++i) {          // wave w owns b = 8w..8w+7
        const int b = wave * 8 + i;
        float zv = pZ[b * NC + lane];      // NC == 64 == wave width
        zv = wave_reduce_sum(zv);
        if (lane == 0) sInvZ[b] = (zv > 0.f) ? 1.f / zv : 0.f;
    }
    __syncthreads();

    {   // normalize this block's slice of the weights output
        const int idx = blockIdx.x * 256 + t;     // 256 blocks x 256 = B*L
        out_weights[idx] *= sInvZ[idx >> 11];     // 2048 weights per b
    }

    const int e = blockIdx.x * 4 + wave;
    const float4* W4 = (const float4*)(W_out + (size_t)e * (2 * D_DIM));
    float4 wrow[8];
    #pragma unroll
    for (int j = 0; j < 8; ++j) wrow[j] = W4[j * 64 + lane];
    #pragma unroll 2
    for (int b = 0; b < B_DIM; ++b) {
        const float4* m4 = (const float4*)(mix_raw + (size_t)b * D_DIM);
        const float4* q4 = (const float4*)(q + (size_t)b * D_DIM);
        const float iz = sInvZ[b];
        float lmix = 0.f, lq = 0.f;
        #pragma unroll
        for (int j = 0; j < 4; ++j) {
            float4 v = m4[j * 64 + lane];
            lmix += v.x * wrow[j].x + v.y * wrow[j].y
                  + v.z * wrow[j].z + v.w * wrow[j].w;
        }
        #pragma unroll
        for (int j = 0; j < 4; ++j) {
            float4 v = q4[j * 64 + lane];
            lq += v.x * wrow[j + 4].x + v.y * wrow[j + 4].y
                + v.z * wrow[j + 4].z + v.w * wrow[j + 4].w;
        }
        float s = wave_reduce_sum(lmix * iz + lq);
        if (lane == 0) out[(size_t)b * D_DIM + e] = tanhf(s);
    }
}

// ---------------------------------------------------------------------------
extern "C" void kernel_launch(void* const* d_in, const int* in_sizes, int n_in,
                              void* d_out, int out_size, void* d_ws, size_t ws_size,
                              hipStream_t stream) {
    const float* query   = (const float*)d_in[0];  // [B,1,D]
    const float* context = (const float*)d_in[1];  // [B,L,D]
    const float* W_in    = (const float*)d_in[2];  // [D,D]
    const float* w_att   = (const float*)d_in[3];  // [2D]
    const float* b_att   = (const float*)d_in[4];  // [1]
    const float* W_out   = (const float*)d_in[5];  // [D,2D]
    const int*   mask    = (const int*)d_in[6];    // [B,L]

    float* out   = (float*)d_out;                  // [B,1,D] flat
    float* out_w = out + (size_t)B_DIM * D_DIM;    // [B,1,L] flat

    // workspace layout (floats), all float4-aligned
    float* ws    = (float*)d_ws;
    float* q     = ws;                               // B*D  = 32768
    float* pZ    = q + (size_t)B_DIM * D_DIM;        // B*NC = 2048
    float* mix   = pZ + B_DIM * NC;                  // B*D  = 32768 (atomic acc)

    k_linear_in<<<D_DIM / 4, 256, 0, stream>>>(query, W_in, q, mix);
    k_scores<<<dim3(NC, B_DIM), 256, 0, stream>>>(context, w_att, mask, q,
                                                  b_att, out_w, pZ, mix);
    k_out<<<D_DIM / 4, 256, 0, stream>>>(mix, q, pZ, W_out, out, out_w);
}